// Round 2
// baseline (926.528 us; speedup 1.0000x reference)
//
#include <hip/hip_runtime.h>
#include <hip/hip_bf16.h>

// GraphSAGE edge classifier, fp32.
// Pipeline (v2 — bucketed counting-sort replaces CSR build):
//  K1 bincount : per-(block,bucket) histogram of dst buckets
//  K2 scan     : exclusive scan of counts[NB*NBLK] -> row
//  K3 binwrite : packed (dst_local<<17|src) entries into exclusive ranges
//  K4 lin1     : y = x@W1l, z = x@W1r  (LDS-tiled, 32 nodes/block)
//  K5 agg1     : per-bucket LDS accumulate -> h1=relu(mean+b1+z) -> p,q
//  K6 agg2     : per-bucket LDS accumulate -> h2=relu(mean+b2+q) -> u,v
//  K7 edge_out : out = log_softmax(u[src] + v[dst] + bc)

#define NBLK 512          // edge-chunk blocks for binning
#define BUCKET_BITS 9
#define BUCKET_SZ 512     // nodes per bucket
#define MAXNB 256         // >= ceil(100000/512)=196

__global__ __launch_bounds__(512) void bincount_kernel(const int* __restrict__ ei,
                                                       int* __restrict__ counts,
                                                       int E, int NB, int chunk) {
  __shared__ int hist[MAXNB];
  for (int i = threadIdx.x; i < NB; i += 512) hist[i] = 0;
  __syncthreads();
  int s = blockIdx.x * chunk;
  int eend = s + chunk; if (eend > E) eend = E;
  for (int e = s + threadIdx.x; e < eend; e += 512)
    atomicAdd(&hist[ei[E + e] >> BUCKET_BITS], 1);
  __syncthreads();
  for (int b = threadIdx.x; b < NB; b += 512)
    counts[b * NBLK + blockIdx.x] = hist[b];
}

#define SCAN_T 1024
#define SCAN_I 16
__global__ __launch_bounds__(SCAN_T) void scan_kernel(const int* __restrict__ cnt,
                                                      int* __restrict__ row, int n) {
  __shared__ int wsum[SCAN_T / 64];
  int lane = threadIdx.x & 63;
  int wid = threadIdx.x >> 6;
  int running = 0;
  for (int base = 0; base < n; base += SCAN_T * SCAN_I) {
    int idx0 = base + threadIdx.x * SCAN_I;
    int v[SCAN_I];
    int tsum = 0;
#pragma unroll
    for (int i = 0; i < SCAN_I; ++i) {
      int ii = idx0 + i;
      v[i] = (ii < n) ? cnt[ii] : 0;
      tsum += v[i];
    }
    int incl = tsum;
#pragma unroll
    for (int d = 1; d < 64; d <<= 1) {
      int t = __shfl_up(incl, d);
      if (lane >= d) incl += t;
    }
    if (lane == 63) wsum[wid] = incl;
    __syncthreads();
    if (wid == 0 && lane < (SCAN_T / 64)) {
      int w = wsum[lane];
#pragma unroll
      for (int d = 1; d < (SCAN_T / 64); d <<= 1) {
        int t = __shfl_up(w, d);
        if (lane >= d) w += t;
      }
      wsum[lane] = w;
    }
    __syncthreads();
    int offset = running + (wid ? wsum[wid - 1] : 0) + (incl - tsum);
#pragma unroll
    for (int i = 0; i < SCAN_I; ++i) {
      int ii = idx0 + i;
      if (ii < n) row[ii] = offset;
      offset += v[i];
    }
    running += wsum[(SCAN_T / 64) - 1];
    __syncthreads();
  }
  if (threadIdx.x == 0) row[n] = running;
}

__global__ __launch_bounds__(512) void binwrite_kernel(const int* __restrict__ ei,
                                                       const int* __restrict__ row,
                                                       int* __restrict__ elist,
                                                       int E, int NB, int chunk) {
  __shared__ int cur[MAXNB];
  for (int b = threadIdx.x; b < NB; b += 512) cur[b] = row[b * NBLK + blockIdx.x];
  __syncthreads();
  int s = blockIdx.x * chunk;
  int eend = s + chunk; if (eend > E) eend = E;
  for (int e = s + threadIdx.x; e < eend; e += 512) {
    int src = ei[e];
    int dst = ei[E + e];
    int b = dst >> BUCKET_BITS;
    int pos = atomicAdd(&cur[b], 1);
    elist[pos] = ((dst & (BUCKET_SZ - 1)) << 17) | src;
  }
}

// y = x@W1l, z = x@W1r ; 32 nodes per 256-thread block
__global__ __launch_bounds__(256) void lin1_kernel(const float* __restrict__ x,
                                                   const float* __restrict__ W1l,
                                                   const float* __restrict__ W1r,
                                                   float* __restrict__ y,
                                                   float* __restrict__ z, int N) {
  __shared__ float Xs[32 * 129];
  __shared__ float Ws[128 * 32];
  int t = threadIdx.x;
  for (int i = t; i < 128 * 16; i += 256) {
    int k = i >> 4, c = i & 15;
    Ws[k * 32 + c] = W1l[i];
    Ws[k * 32 + 16 + c] = W1r[i];
  }
  int nb = blockIdx.x * 32;
  const float4* xg = (const float4*)(x + (size_t)nb * 128);
  for (int i4 = t; i4 < 32 * 32; i4 += 256) {
    float4 val = xg[i4];
    int r = i4 >> 5, c4 = (i4 & 31) * 4;
    float* dp = &Xs[r * 129 + c4];
    dp[0] = val.x; dp[1] = val.y; dp[2] = val.z; dp[3] = val.w;
  }
  __syncthreads();
  int n = t & 31, cg = t >> 5;
  float a0 = 0.f, a1 = 0.f, a2 = 0.f, a3 = 0.f;
  for (int k = 0; k < 128; ++k) {
    float xv = Xs[n * 129 + k];
    const float* wr = &Ws[k * 32 + cg * 4];
    a0 += xv * wr[0]; a1 += xv * wr[1]; a2 += xv * wr[2]; a3 += xv * wr[3];
  }
  int node = nb + n;
  if (node < N) {
    int c = cg * 4;
    float* op = (c < 16) ? (y + (size_t)node * 16 + c)
                         : (z + (size_t)node * 16 + (c - 16));
    op[0] = a0; op[1] = a1; op[2] = a2; op[3] = a3;
  }
}

// Per-bucket LDS accumulation; epilogue: h=relu(mean+b1+z), p=h@W2l, q=h@W2r
__global__ __launch_bounds__(1024) void agg1_kernel(const float* __restrict__ y,
                                                    const float* __restrict__ z,
                                                    const int* __restrict__ row,
                                                    const int* __restrict__ elist,
                                                    const float* __restrict__ b1,
                                                    const float* __restrict__ W2l,
                                                    const float* __restrict__ W2r,
                                                    float* __restrict__ p,
                                                    float* __restrict__ q, int N) {
  __shared__ float acc[BUCKET_SZ * 17];   // stride 17 -> spread banks
  __shared__ int   deg[BUCKET_SZ];
  __shared__ float Wl[256], Wr[256], bs[16];
  int t = threadIdx.x;
  for (int i = t; i < BUCKET_SZ * 17; i += 1024) acc[i] = 0.f;
  for (int i = t; i < BUCKET_SZ; i += 1024) deg[i] = 0;
  if (t < 256) { Wl[t] = W2l[t]; Wr[t] = W2r[t]; }
  if (t < 16) bs[t] = b1[t];
  __syncthreads();
  int b = blockIdx.x;
  int beg = row[b * NBLK];
  int end = row[(b + 1) * NBLK];
  for (int e = beg + t; e < end; e += 1024) {
    unsigned ent = (unsigned)elist[e];
    int src = ent & 0x1FFFF;
    int dl = ent >> 17;
    const float4* yp = (const float4*)(y + (size_t)src * 16);
    float4 v0 = yp[0], v1 = yp[1], v2 = yp[2], v3 = yp[3];
    float* a = &acc[dl * 17];
    atomicAdd(&a[0], v0.x);  atomicAdd(&a[1], v0.y);
    atomicAdd(&a[2], v0.z);  atomicAdd(&a[3], v0.w);
    atomicAdd(&a[4], v1.x);  atomicAdd(&a[5], v1.y);
    atomicAdd(&a[6], v1.z);  atomicAdd(&a[7], v1.w);
    atomicAdd(&a[8], v2.x);  atomicAdd(&a[9], v2.y);
    atomicAdd(&a[10], v2.z); atomicAdd(&a[11], v2.w);
    atomicAdd(&a[12], v3.x); atomicAdd(&a[13], v3.y);
    atomicAdd(&a[14], v3.z); atomicAdd(&a[15], v3.w);
    atomicAdd(&deg[dl], 1);
  }
  __syncthreads();
  int base = b << BUCKET_BITS;
  // phase A: acc -> h (in place)
  for (int nb0 = 0; nb0 < BUCKET_SZ; nb0 += 64) {
    int dl = nb0 + (t >> 4), kk = t & 15;
    int node = base + dl;
    if (node < N) {
      int d = deg[dl];
      float mean = acc[dl * 17 + kk] / (float)(d > 0 ? d : 1);
      acc[dl * 17 + kk] = fmaxf(mean + bs[kk] + z[(size_t)node * 16 + kk], 0.f);
    }
  }
  __syncthreads();
  // phase B: p,q
  for (int nb0 = 0; nb0 < BUCKET_SZ; nb0 += 64) {
    int dl = nb0 + (t >> 4), k = t & 15;
    int node = base + dl;
    if (node < N) {
      const float* h = &acc[dl * 17];
      float pa = 0.f, qa = 0.f;
#pragma unroll
      for (int kk = 0; kk < 16; ++kk) {
        float hv = h[kk];
        pa += hv * Wl[kk * 16 + k];
        qa += hv * Wr[kk * 16 + k];
      }
      p[(size_t)node * 16 + k] = pa;
      q[(size_t)node * 16 + k] = qa;
    }
  }
}

// Per-bucket LDS accumulation; epilogue: h=relu(mean+b2+q), u=h@Wc[:16], v=h@Wc[16:]
__global__ __launch_bounds__(1024) void agg2_kernel(const float* __restrict__ p,
                                                    const float* __restrict__ q,
                                                    const int* __restrict__ row,
                                                    const int* __restrict__ elist,
                                                    const float* __restrict__ b2,
                                                    const float* __restrict__ Wc,
                                                    float* __restrict__ U,
                                                    float* __restrict__ V, int N) {
  __shared__ float acc[BUCKET_SZ * 17];
  __shared__ int   deg[BUCKET_SZ];
  __shared__ float Wcs[256], bs[16];
  int t = threadIdx.x;
  for (int i = t; i < BUCKET_SZ * 17; i += 1024) acc[i] = 0.f;
  for (int i = t; i < BUCKET_SZ; i += 1024) deg[i] = 0;
  if (t < 256) Wcs[t] = Wc[t];
  if (t < 16) bs[t] = b2[t];
  __syncthreads();
  int b = blockIdx.x;
  int beg = row[b * NBLK];
  int end = row[(b + 1) * NBLK];
  for (int e = beg + t; e < end; e += 1024) {
    unsigned ent = (unsigned)elist[e];
    int src = ent & 0x1FFFF;
    int dl = ent >> 17;
    const float4* pp = (const float4*)(p + (size_t)src * 16);
    float4 v0 = pp[0], v1 = pp[1], v2 = pp[2], v3 = pp[3];
    float* a = &acc[dl * 17];
    atomicAdd(&a[0], v0.x);  atomicAdd(&a[1], v0.y);
    atomicAdd(&a[2], v0.z);  atomicAdd(&a[3], v0.w);
    atomicAdd(&a[4], v1.x);  atomicAdd(&a[5], v1.y);
    atomicAdd(&a[6], v1.z);  atomicAdd(&a[7], v1.w);
    atomicAdd(&a[8], v2.x);  atomicAdd(&a[9], v2.y);
    atomicAdd(&a[10], v2.z); atomicAdd(&a[11], v2.w);
    atomicAdd(&a[12], v3.x); atomicAdd(&a[13], v3.y);
    atomicAdd(&a[14], v3.z); atomicAdd(&a[15], v3.w);
    atomicAdd(&deg[dl], 1);
  }
  __syncthreads();
  int base = b << BUCKET_BITS;
  for (int nb0 = 0; nb0 < BUCKET_SZ; nb0 += 64) {
    int dl = nb0 + (t >> 4), kk = t & 15;
    int node = base + dl;
    if (node < N) {
      int d = deg[dl];
      float mean = acc[dl * 17 + kk] / (float)(d > 0 ? d : 1);
      acc[dl * 17 + kk] = fmaxf(mean + bs[kk] + q[(size_t)node * 16 + kk], 0.f);
    }
  }
  __syncthreads();
  for (int nb0 = 0; nb0 < BUCKET_SZ; nb0 += 64) {
    int dl = nb0 + (t >> 4), k = t & 15;
    int node = base + dl;
    if (node < N) {
      const float* h = &acc[dl * 17];
      int wbase = (k < 8) ? 0 : 16;
      int c = k & 7;
      float o = 0.f;
#pragma unroll
      for (int kk = 0; kk < 16; ++kk)
        o += h[kk] * Wcs[(wbase + kk) * 8 + c];
      if (k < 8) U[(size_t)node * 8 + c] = o;
      else       V[(size_t)node * 8 + c] = o;
    }
  }
}

__global__ __launch_bounds__(256) void edge_out_kernel(const int* __restrict__ ei,
                                                       const float* __restrict__ U,
                                                       const float* __restrict__ V,
                                                       const float* __restrict__ bc,
                                                       float* __restrict__ out, int E) {
  int e = blockIdx.x * 256 + threadIdx.x;
  if (e >= E) return;
  int src = ei[e];
  int dst = ei[E + e];
  const float4* up = (const float4*)(U + (size_t)src * 8);
  const float4* vp = (const float4*)(V + (size_t)dst * 8);
  float4 a0 = up[0], a1 = up[1];
  float4 b0 = vp[0], b1 = vp[1];
  float4 c0 = ((const float4*)bc)[0], c1 = ((const float4*)bc)[1];
  float t[8];
  t[0] = a0.x + b0.x + c0.x; t[1] = a0.y + b0.y + c0.y;
  t[2] = a0.z + b0.z + c0.z; t[3] = a0.w + b0.w + c0.w;
  t[4] = a1.x + b1.x + c1.x; t[5] = a1.y + b1.y + c1.y;
  t[6] = a1.z + b1.z + c1.z; t[7] = a1.w + b1.w + c1.w;
  float m = t[0];
#pragma unroll
  for (int c = 1; c < 8; ++c) m = fmaxf(m, t[c]);
  float s = 0.f;
#pragma unroll
  for (int c = 0; c < 8; ++c) s += __expf(t[c] - m);
  float lse = m + __logf(s);
  float4 o0 = make_float4(t[0] - lse, t[1] - lse, t[2] - lse, t[3] - lse);
  float4 o1 = make_float4(t[4] - lse, t[5] - lse, t[6] - lse, t[7] - lse);
  float4* op = (float4*)(out + (size_t)e * 8);
  op[0] = o0; op[1] = o1;
}

extern "C" void kernel_launch(void* const* d_in, const int* in_sizes, int n_in,
                              void* d_out, int out_size, void* d_ws, size_t ws_size,
                              hipStream_t stream) {
  const float* x   = (const float*)d_in[0];
  const int*   ei  = (const int*)d_in[1];
  const float* W1l = (const float*)d_in[2];
  const float* b1  = (const float*)d_in[3];
  const float* W1r = (const float*)d_in[4];
  const float* W2l = (const float*)d_in[5];
  const float* b2  = (const float*)d_in[6];
  const float* W2r = (const float*)d_in[7];
  const float* Wc  = (const float*)d_in[8];
  const float* bc  = (const float*)d_in[9];
  float* out = (float*)d_out;

  const int N = in_sizes[0] / 128;   // 100000
  const int E = in_sizes[1] / 2;     // 3200000
  const size_t N16 = (size_t)N * 16;
  const int NB = (N + BUCKET_SZ - 1) >> BUCKET_BITS;   // 196
  const int chunk = (E + NBLK - 1) / NBLK;

  float* A = (float*)d_ws;           // y, later u
  float* B = A + N16;                // z, later v
  float* C = B + N16;                // p
  float* D = C + N16;                // q
  int* counts = (int*)(D + N16);     // NB*NBLK
  int* row    = counts + NB * NBLK;  // NB*NBLK + 1
  int* elist  = row + NB * NBLK + 1; // E

  bincount_kernel<<<NBLK, 512, 0, stream>>>(ei, counts, E, NB, chunk);
  scan_kernel<<<1, SCAN_T, 0, stream>>>(counts, row, NB * NBLK);
  binwrite_kernel<<<NBLK, 512, 0, stream>>>(ei, row, elist, E, NB, chunk);

  lin1_kernel<<<(N + 31) / 32, 256, 0, stream>>>(x, W1l, W1r, A, B, N);

  agg1_kernel<<<NB, 1024, 0, stream>>>(A, B, row, elist, b1, W2l, W2r, C, D, N);
  agg2_kernel<<<NB, 1024, 0, stream>>>(C, D, row, elist, b2, Wc, A, B, N);

  int egrid = (E + 255) / 256;
  edge_out_kernel<<<egrid, 256, 0, stream>>>(ei, A, B, bc, out, E);
}

// Round 3
// 342.258 us; speedup vs baseline: 2.7071x; 2.7071x over previous
//
#include <hip/hip_runtime.h>
#include <hip/hip_bf16.h>

// GraphSAGE edge classifier, fp32.
// Pipeline (v3 — bucketed counting-sort -> full CSR, atomic-free aggregation):
//  K1 bincount : per-(block,bucket) histogram of dst buckets
//  K2 scan     : exclusive scan of counts[NB*NBLK] -> row
//  K3 binwrite : packed (dst_local<<17|src) entries into exclusive bucket ranges
//  K3b sort    : per-bucket LDS counting sort (in-place) -> srclist + row_csr
//  K4 lin1     : y = x@W1l, z = x@W1r  (LDS-tiled, 32 nodes/block)
//  K5 agg1     : CSR gather mean -> h1=relu(+b1+z) -> p=h1@W2l, q=h1@W2r
//  K6 agg2     : CSR gather mean -> h2=relu(+b2+q) -> u=h2@Wc[:16], v=h2@Wc[16:]
//  K7 edge_out : out = log_softmax(u[src] + v[dst] + bc)

#define NBLK 512          // edge-chunk blocks for binning
#define BUCKET_BITS 9
#define BUCKET_SZ 512     // nodes per bucket
#define MAXNB 256         // >= ceil(100000/512)=196
#define STAGE_CAP 36000   // bucket stage capacity (mean 16384, +150 sigma)

__global__ __launch_bounds__(512) void bincount_kernel(const int* __restrict__ ei,
                                                       int* __restrict__ counts,
                                                       int E, int NB, int chunk) {
  __shared__ int hist[MAXNB];
  for (int i = threadIdx.x; i < NB; i += 512) hist[i] = 0;
  __syncthreads();
  int s = blockIdx.x * chunk;
  int eend = s + chunk; if (eend > E) eend = E;
  for (int e = s + threadIdx.x; e < eend; e += 512)
    atomicAdd(&hist[ei[E + e] >> BUCKET_BITS], 1);
  __syncthreads();
  for (int b = threadIdx.x; b < NB; b += 512)
    counts[b * NBLK + blockIdx.x] = hist[b];
}

#define SCAN_T 1024
#define SCAN_I 16
__global__ __launch_bounds__(SCAN_T) void scan_kernel(const int* __restrict__ cnt,
                                                      int* __restrict__ row, int n) {
  __shared__ int wsum[SCAN_T / 64];
  int lane = threadIdx.x & 63;
  int wid = threadIdx.x >> 6;
  int running = 0;
  for (int base = 0; base < n; base += SCAN_T * SCAN_I) {
    int idx0 = base + threadIdx.x * SCAN_I;
    int v[SCAN_I];
    int tsum = 0;
#pragma unroll
    for (int i = 0; i < SCAN_I; ++i) {
      int ii = idx0 + i;
      v[i] = (ii < n) ? cnt[ii] : 0;
      tsum += v[i];
    }
    int incl = tsum;
#pragma unroll
    for (int d = 1; d < 64; d <<= 1) {
      int t = __shfl_up(incl, d);
      if (lane >= d) incl += t;
    }
    if (lane == 63) wsum[wid] = incl;
    __syncthreads();
    if (wid == 0 && lane < (SCAN_T / 64)) {
      int w = wsum[lane];
#pragma unroll
      for (int d = 1; d < (SCAN_T / 64); d <<= 1) {
        int t = __shfl_up(w, d);
        if (lane >= d) w += t;
      }
      wsum[lane] = w;
    }
    __syncthreads();
    int offset = running + (wid ? wsum[wid - 1] : 0) + (incl - tsum);
#pragma unroll
    for (int i = 0; i < SCAN_I; ++i) {
      int ii = idx0 + i;
      if (ii < n) row[ii] = offset;
      offset += v[i];
    }
    running += wsum[(SCAN_T / 64) - 1];
    __syncthreads();
  }
  if (threadIdx.x == 0) row[n] = running;
}

__global__ __launch_bounds__(512) void binwrite_kernel(const int* __restrict__ ei,
                                                       const int* __restrict__ row,
                                                       int* __restrict__ elist,
                                                       int E, int NB, int chunk) {
  __shared__ int cur[MAXNB];
  for (int b = threadIdx.x; b < NB; b += 512) cur[b] = row[b * NBLK + blockIdx.x];
  __syncthreads();
  int s = blockIdx.x * chunk;
  int eend = s + chunk; if (eend > E) eend = E;
  for (int e = s + threadIdx.x; e < eend; e += 512) {
    int src = ei[e];
    int dst = ei[E + e];
    int b = dst >> BUCKET_BITS;
    int pos = atomicAdd(&cur[b], 1);
    elist[pos] = ((dst & (BUCKET_SZ - 1)) << 17) | src;
  }
}

// Per-bucket counting sort. Stages the bucket's packed entries in LDS, builds a
// 512-bin histogram, scans it, writes row_csr, then scatters plain src ids back
// IN PLACE over the bucket's own elist range (block-exclusive -> race-free).
__global__ __launch_bounds__(1024) void sort_kernel(int* __restrict__ elist,
                                                    const int* __restrict__ row,
                                                    int* __restrict__ row_csr,
                                                    int N) {
  extern __shared__ int sm[];
  int* stage = sm;                 // STAGE_CAP
  int* hist  = sm + STAGE_CAP;     // 512 (becomes excl offsets, then cursors)
  int* wtmp  = hist + 512;         // 16
  int t = threadIdx.x;
  int b = blockIdx.x;
  int beg = row[b * NBLK];
  int end = row[(b + 1) * NBLK];
  int cnt = end - beg;
  if (cnt > STAGE_CAP) cnt = STAGE_CAP;   // safety clamp (statistically unreachable)
  for (int i = t; i < cnt; i += 1024) stage[i] = elist[beg + i];
  if (t < 512) hist[t] = 0;
  __syncthreads();
  for (int i = t; i < cnt; i += 1024)
    atomicAdd(&hist[((unsigned)stage[i]) >> 17], 1);
  __syncthreads();
  // exclusive scan of hist[0..511]
  int lane = t & 63;
  int wv = t >> 6;
  int v = (t < 512) ? hist[t] : 0;
  int incl = v;
#pragma unroll
  for (int d = 1; d < 64; d <<= 1) {
    int u = __shfl_up(incl, d);
    if (lane >= d) incl += u;
  }
  if (t < 512 && lane == 63) wtmp[wv] = incl;
  __syncthreads();
  if (t < 64) {
    int w = (t < 8) ? wtmp[t] : 0;
#pragma unroll
    for (int d = 1; d < 8; d <<= 1) {
      int u = __shfl_up(w, d);
      if (lane >= d) w += u;
    }
    if (t < 8) wtmp[t] = w;
  }
  __syncthreads();
  if (t < 512) {
    int excl = ((wv > 0) ? wtmp[wv - 1] : 0) + (incl - v);
    hist[t] = excl;                       // cursor for scatter
    int node = (b << BUCKET_BITS) + t;
    if (node <= N) row_csr[node] = beg + excl;
  }
  __syncthreads();
  for (int i = t; i < cnt; i += 1024) {
    unsigned ent = (unsigned)stage[i];
    int pos = atomicAdd(&hist[ent >> 17], 1);
    elist[beg + pos] = ent & 0x1FFFF;
  }
}

// y = x@W1l, z = x@W1r ; 32 nodes per 256-thread block
__global__ __launch_bounds__(256) void lin1_kernel(const float* __restrict__ x,
                                                   const float* __restrict__ W1l,
                                                   const float* __restrict__ W1r,
                                                   float* __restrict__ y,
                                                   float* __restrict__ z, int N) {
  __shared__ float Xs[32 * 129];
  __shared__ float Ws[128 * 32];
  int t = threadIdx.x;
  for (int i = t; i < 128 * 16; i += 256) {
    int k = i >> 4, c = i & 15;
    Ws[k * 32 + c] = W1l[i];
    Ws[k * 32 + 16 + c] = W1r[i];
  }
  int nb = blockIdx.x * 32;
  const float4* xg = (const float4*)(x + (size_t)nb * 128);
  for (int i4 = t; i4 < 32 * 32; i4 += 256) {
    float4 val = xg[i4];
    int r = i4 >> 5, c4 = (i4 & 31) * 4;
    float* dp = &Xs[r * 129 + c4];
    dp[0] = val.x; dp[1] = val.y; dp[2] = val.z; dp[3] = val.w;
  }
  __syncthreads();
  int n = t & 31, cg = t >> 5;
  float a0 = 0.f, a1 = 0.f, a2 = 0.f, a3 = 0.f;
  for (int k = 0; k < 128; ++k) {
    float xv = Xs[n * 129 + k];
    const float* wr = &Ws[k * 32 + cg * 4];
    a0 += xv * wr[0]; a1 += xv * wr[1]; a2 += xv * wr[2]; a3 += xv * wr[3];
  }
  int node = nb + n;
  if (node < N) {
    int c = cg * 4;
    float* op = (c < 16) ? (y + (size_t)node * 16 + c)
                         : (z + (size_t)node * 16 + (c - 16));
    op[0] = a0; op[1] = a1; op[2] = a2; op[3] = a3;
  }
}

// CSR gather mean -> h=relu(+b1+z) -> p=h@W2l, q=h@W2r ; 16 lanes/node
__global__ __launch_bounds__(256) void agg1_kernel(const float* __restrict__ y,
                                                   const float* __restrict__ z,
                                                   const int* __restrict__ row_csr,
                                                   const int* __restrict__ srclist,
                                                   const float* __restrict__ b1,
                                                   const float* __restrict__ W2l,
                                                   const float* __restrict__ W2r,
                                                   float* __restrict__ p,
                                                   float* __restrict__ q, int N) {
  int g = (blockIdx.x * 256 + threadIdx.x) >> 4;
  int k = threadIdx.x & 15;
  if (g >= N) return;
  int beg = row_csr[g], end = row_csr[g + 1];
  float acc = 0.f;
  int j = beg;
  for (; j + 4 <= end; j += 4) {
    int s0 = srclist[j], s1 = srclist[j + 1];
    int s2 = srclist[j + 2], s3 = srclist[j + 3];
    acc += y[(size_t)s0 * 16 + k];
    acc += y[(size_t)s1 * 16 + k];
    acc += y[(size_t)s2 * 16 + k];
    acc += y[(size_t)s3 * 16 + k];
  }
  for (; j < end; ++j) acc += y[(size_t)srclist[j] * 16 + k];
  int deg = end - beg;
  float mean = acc / (float)(deg > 0 ? deg : 1);
  float h = fmaxf(mean + b1[k] + z[(size_t)g * 16 + k], 0.f);
  float pa = 0.f, qa = 0.f;
#pragma unroll
  for (int kk = 0; kk < 16; ++kk) {
    float hk = __shfl(h, kk, 16);
    pa += hk * W2l[kk * 16 + k];
    qa += hk * W2r[kk * 16 + k];
  }
  p[(size_t)g * 16 + k] = pa;
  q[(size_t)g * 16 + k] = qa;
}

// CSR gather mean -> h=relu(+b2+q) -> u=h@Wc[:16], v=h@Wc[16:]
__global__ __launch_bounds__(256) void agg2_kernel(const float* __restrict__ p,
                                                   const float* __restrict__ q,
                                                   const int* __restrict__ row_csr,
                                                   const int* __restrict__ srclist,
                                                   const float* __restrict__ b2,
                                                   const float* __restrict__ Wc,
                                                   float* __restrict__ U,
                                                   float* __restrict__ V, int N) {
  int g = (blockIdx.x * 256 + threadIdx.x) >> 4;
  int k = threadIdx.x & 15;
  if (g >= N) return;
  int beg = row_csr[g], end = row_csr[g + 1];
  float acc = 0.f;
  int j = beg;
  for (; j + 4 <= end; j += 4) {
    int s0 = srclist[j], s1 = srclist[j + 1];
    int s2 = srclist[j + 2], s3 = srclist[j + 3];
    acc += p[(size_t)s0 * 16 + k];
    acc += p[(size_t)s1 * 16 + k];
    acc += p[(size_t)s2 * 16 + k];
    acc += p[(size_t)s3 * 16 + k];
  }
  for (; j < end; ++j) acc += p[(size_t)srclist[j] * 16 + k];
  int deg = end - beg;
  float mean = acc / (float)(deg > 0 ? deg : 1);
  float h = fmaxf(mean + b2[k] + q[(size_t)g * 16 + k], 0.f);
  int wbase = (k < 8) ? 0 : 16;
  int c = k & 7;
  float o = 0.f;
#pragma unroll
  for (int kk = 0; kk < 16; ++kk) {
    float hk = __shfl(h, kk, 16);
    o += hk * Wc[(wbase + kk) * 8 + c];
  }
  if (k < 8) U[(size_t)g * 8 + c] = o;
  else       V[(size_t)g * 8 + c] = o;
}

__global__ __launch_bounds__(256) void edge_out_kernel(const int* __restrict__ ei,
                                                       const float* __restrict__ U,
                                                       const float* __restrict__ V,
                                                       const float* __restrict__ bc,
                                                       float* __restrict__ out, int E) {
  int e = blockIdx.x * 256 + threadIdx.x;
  if (e >= E) return;
  int src = ei[e];
  int dst = ei[E + e];
  const float4* up = (const float4*)(U + (size_t)src * 8);
  const float4* vp = (const float4*)(V + (size_t)dst * 8);
  float4 a0 = up[0], a1 = up[1];
  float4 b0 = vp[0], b1 = vp[1];
  float4 c0 = ((const float4*)bc)[0], c1 = ((const float4*)bc)[1];
  float t[8];
  t[0] = a0.x + b0.x + c0.x; t[1] = a0.y + b0.y + c0.y;
  t[2] = a0.z + b0.z + c0.z; t[3] = a0.w + b0.w + c0.w;
  t[4] = a1.x + b1.x + c1.x; t[5] = a1.y + b1.y + c1.y;
  t[6] = a1.z + b1.z + c1.z; t[7] = a1.w + b1.w + c1.w;
  float m = t[0];
#pragma unroll
  for (int c = 1; c < 8; ++c) m = fmaxf(m, t[c]);
  float s = 0.f;
#pragma unroll
  for (int c = 0; c < 8; ++c) s += __expf(t[c] - m);
  float lse = m + __logf(s);
  float4 o0 = make_float4(t[0] - lse, t[1] - lse, t[2] - lse, t[3] - lse);
  float4 o1 = make_float4(t[4] - lse, t[5] - lse, t[6] - lse, t[7] - lse);
  float4* op = (float4*)(out + (size_t)e * 8);
  op[0] = o0; op[1] = o1;
}

extern "C" void kernel_launch(void* const* d_in, const int* in_sizes, int n_in,
                              void* d_out, int out_size, void* d_ws, size_t ws_size,
                              hipStream_t stream) {
  const float* x   = (const float*)d_in[0];
  const int*   ei  = (const int*)d_in[1];
  const float* W1l = (const float*)d_in[2];
  const float* b1  = (const float*)d_in[3];
  const float* W1r = (const float*)d_in[4];
  const float* W2l = (const float*)d_in[5];
  const float* b2  = (const float*)d_in[6];
  const float* W2r = (const float*)d_in[7];
  const float* Wc  = (const float*)d_in[8];
  const float* bc  = (const float*)d_in[9];
  float* out = (float*)d_out;

  const int N = in_sizes[0] / 128;   // 100000
  const int E = in_sizes[1] / 2;     // 3200000
  const size_t N16 = (size_t)N * 16;
  const int NB = (N + BUCKET_SZ - 1) >> BUCKET_BITS;   // 196
  const int chunk = (E + NBLK - 1) / NBLK;

  float* A = (float*)d_ws;             // y, later u
  float* B = A + N16;                  // z, later v
  float* C = B + N16;                  // p
  float* D = C + N16;                  // q
  int* counts  = (int*)(D + N16);      // NB*NBLK
  int* row     = counts + NB * NBLK;   // NB*NBLK + 1
  int* elist   = row + NB * NBLK + 1;  // E  (packed, then in-place sorted src)
  int* row_csr = elist + E;            // N + 1

  bincount_kernel<<<NBLK, 512, 0, stream>>>(ei, counts, E, NB, chunk);
  scan_kernel<<<1, SCAN_T, 0, stream>>>(counts, row, NB * NBLK);
  binwrite_kernel<<<NBLK, 512, 0, stream>>>(ei, row, elist, E, NB, chunk);
  size_t smem = (STAGE_CAP + 512 + 16) * sizeof(int);   // ~146 KB
  sort_kernel<<<NB, 1024, smem, stream>>>(elist, row, row_csr, N);

  lin1_kernel<<<(N + 31) / 32, 256, 0, stream>>>(x, W1l, W1r, A, B, N);

  int ngrid = (N * 16 + 255) / 256;
  agg1_kernel<<<ngrid, 256, 0, stream>>>(A, B, row_csr, elist, b1, W2l, W2r, C, D, N);
  agg2_kernel<<<ngrid, 256, 0, stream>>>(C, D, row_csr, elist, b2, Wc, A, B, N);

  int egrid = (E + 255) / 256;
  edge_out_kernel<<<egrid, 256, 0, stream>>>(ei, A, B, bc, out, E);
}

// Round 4
// 256.538 us; speedup vs baseline: 3.6117x; 1.3341x over previous
//
#include <hip/hip_runtime.h>
#include <hip/hip_bf16.h>

// GraphSAGE edge classifier, fp32.
// Pipeline (v4 — hierarchical scan replaces the single-block scan):
//  K1 bincount : per-(block,bucket) histogram of dst buckets
//  K2a scan1   : per-bucket local exclusive scan of its 512 chunk-counts + total
//  K2b scan2   : single-block exclusive scan of 196 bucket totals -> bstart
//  K3 binwrite : packed (dst_local<<17|src) entries into exclusive bucket ranges
//  K3b sort    : per-bucket LDS counting sort (in-place) -> srclist + row_csr
//  K4 lin1     : y = x@W1l, z = x@W1r  (LDS-tiled, 32 nodes/block)
//  K5 agg1     : CSR gather mean -> h1=relu(+b1+z) -> p=h1@W2l, q=h1@W2r
//  K6 agg2     : CSR gather mean -> h2=relu(+b2+q) -> u=h2@Wc[:16], v=h2@Wc[16:]
//  K7 edge_out : out = log_softmax(u[src] + v[dst] + bc)

#define NBLK 512          // edge-chunk blocks for binning (== scan1 width)
#define BUCKET_BITS 9
#define BUCKET_SZ 512     // nodes per bucket
#define MAXNB 256         // >= ceil(100000/512)=196
#define STAGE_CAP 36000   // bucket stage capacity (mean 16384, huge margin)

__global__ __launch_bounds__(512) void bincount_kernel(const int* __restrict__ ei,
                                                       int* __restrict__ counts,
                                                       int E, int NB, int chunk) {
  __shared__ int hist[MAXNB];
  for (int i = threadIdx.x; i < NB; i += 512) hist[i] = 0;
  __syncthreads();
  int s = blockIdx.x * chunk;
  int eend = s + chunk; if (eend > E) eend = E;
  for (int e = s + threadIdx.x; e < eend; e += 512)
    atomicAdd(&hist[ei[E + e] >> BUCKET_BITS], 1);
  __syncthreads();
  for (int b = threadIdx.x; b < NB; b += 512)
    counts[b * NBLK + blockIdx.x] = hist[b];
}

// Per-bucket local exclusive scan: one thread per chunk-count.
__global__ __launch_bounds__(512) void scan1_kernel(const int* __restrict__ counts,
                                                    int* __restrict__ locoff,
                                                    int* __restrict__ total) {
  __shared__ int wsum[8];
  int b = blockIdx.x;
  int t = threadIdx.x;
  int lane = t & 63, wid = t >> 6;
  int v = counts[b * NBLK + t];
  int incl = v;
#pragma unroll
  for (int d = 1; d < 64; d <<= 1) {
    int u = __shfl_up(incl, d);
    if (lane >= d) incl += u;
  }
  if (lane == 63) wsum[wid] = incl;
  __syncthreads();
  if (t < 64) {
    int w = (t < 8) ? wsum[t] : 0;
#pragma unroll
    for (int d = 1; d < 8; d <<= 1) {
      int u = __shfl_up(w, d);
      if (lane >= d) w += u;
    }
    if (t < 8) wsum[t] = w;
  }
  __syncthreads();
  int excl = ((wid > 0) ? wsum[wid - 1] : 0) + (incl - v);
  locoff[b * NBLK + t] = excl;
  if (t == NBLK - 1) total[b] = excl + v;
}

// Single small block: exclusive scan of NB (<=256) bucket totals.
__global__ __launch_bounds__(256) void scan2_kernel(const int* __restrict__ total,
                                                    int* __restrict__ bstart, int NB) {
  __shared__ int wsum[4];
  int t = threadIdx.x;
  int lane = t & 63, wid = t >> 6;
  int v = (t < NB) ? total[t] : 0;
  int incl = v;
#pragma unroll
  for (int d = 1; d < 64; d <<= 1) {
    int u = __shfl_up(incl, d);
    if (lane >= d) incl += u;
  }
  if (lane == 63) wsum[wid] = incl;
  __syncthreads();
  if (t < 64) {
    int w = (t < 4) ? wsum[t] : 0;
#pragma unroll
    for (int d = 1; d < 4; d <<= 1) {
      int u = __shfl_up(w, d);
      if (lane >= d) w += u;
    }
    if (t < 4) wsum[t] = w;
  }
  __syncthreads();
  int excl = ((wid > 0) ? wsum[wid - 1] : 0) + (incl - v);
  if (t <= NB) bstart[t] = excl;   // t==NB gets full sum (=E)
}

__global__ __launch_bounds__(512) void binwrite_kernel(const int* __restrict__ ei,
                                                       const int* __restrict__ locoff,
                                                       const int* __restrict__ bstart,
                                                       int* __restrict__ elist,
                                                       int E, int NB, int chunk) {
  __shared__ int cur[MAXNB];
  for (int b = threadIdx.x; b < NB; b += 512)
    cur[b] = bstart[b] + locoff[b * NBLK + blockIdx.x];
  __syncthreads();
  int s = blockIdx.x * chunk;
  int eend = s + chunk; if (eend > E) eend = E;
  for (int e = s + threadIdx.x; e < eend; e += 512) {
    int src = ei[e];
    int dst = ei[E + e];
    int b = dst >> BUCKET_BITS;
    int pos = atomicAdd(&cur[b], 1);
    elist[pos] = ((dst & (BUCKET_SZ - 1)) << 17) | src;
  }
}

// Per-bucket counting sort. Stages the bucket's packed entries in LDS, builds a
// 512-bin histogram, scans it, writes row_csr, then scatters plain src ids back
// IN PLACE over the bucket's own elist range (block-exclusive -> race-free).
__global__ __launch_bounds__(1024) void sort_kernel(int* __restrict__ elist,
                                                    const int* __restrict__ bstart,
                                                    int* __restrict__ row_csr,
                                                    int N) {
  extern __shared__ int sm[];
  int* stage = sm;                 // STAGE_CAP
  int* hist  = sm + STAGE_CAP;     // 512 (becomes excl offsets, then cursors)
  int* wtmp  = hist + 512;         // 16
  int t = threadIdx.x;
  int b = blockIdx.x;
  int beg = bstart[b];
  int end = bstart[b + 1];
  int cnt = end - beg;
  if (cnt > STAGE_CAP) cnt = STAGE_CAP;   // safety clamp (statistically unreachable)
  for (int i = t; i < cnt; i += 1024) stage[i] = elist[beg + i];
  if (t < 512) hist[t] = 0;
  __syncthreads();
  for (int i = t; i < cnt; i += 1024)
    atomicAdd(&hist[((unsigned)stage[i]) >> 17], 1);
  __syncthreads();
  // exclusive scan of hist[0..511]
  int lane = t & 63;
  int wv = t >> 6;
  int v = (t < 512) ? hist[t] : 0;
  int incl = v;
#pragma unroll
  for (int d = 1; d < 64; d <<= 1) {
    int u = __shfl_up(incl, d);
    if (lane >= d) incl += u;
  }
  if (t < 512 && lane == 63) wtmp[wv] = incl;
  __syncthreads();
  if (t < 64) {
    int w = (t < 8) ? wtmp[t] : 0;
#pragma unroll
    for (int d = 1; d < 8; d <<= 1) {
      int u = __shfl_up(w, d);
      if (lane >= d) w += u;
    }
    if (t < 8) wtmp[t] = w;
  }
  __syncthreads();
  if (t < 512) {
    int excl = ((wv > 0) ? wtmp[wv - 1] : 0) + (incl - v);
    hist[t] = excl;                       // cursor for scatter
    int node = (b << BUCKET_BITS) + t;
    if (node <= N) row_csr[node] = beg + excl;
  }
  __syncthreads();
  for (int i = t; i < cnt; i += 1024) {
    unsigned ent = (unsigned)stage[i];
    int pos = atomicAdd(&hist[ent >> 17], 1);
    elist[beg + pos] = ent & 0x1FFFF;
  }
}

// y = x@W1l, z = x@W1r ; 32 nodes per 256-thread block
__global__ __launch_bounds__(256) void lin1_kernel(const float* __restrict__ x,
                                                   const float* __restrict__ W1l,
                                                   const float* __restrict__ W1r,
                                                   float* __restrict__ y,
                                                   float* __restrict__ z, int N) {
  __shared__ float Xs[32 * 129];
  __shared__ float Ws[128 * 32];
  int t = threadIdx.x;
  for (int i = t; i < 128 * 16; i += 256) {
    int k = i >> 4, c = i & 15;
    Ws[k * 32 + c] = W1l[i];
    Ws[k * 32 + 16 + c] = W1r[i];
  }
  int nb = blockIdx.x * 32;
  const float4* xg = (const float4*)(x + (size_t)nb * 128);
  for (int i4 = t; i4 < 32 * 32; i4 += 256) {
    float4 val = xg[i4];
    int r = i4 >> 5, c4 = (i4 & 31) * 4;
    float* dp = &Xs[r * 129 + c4];
    dp[0] = val.x; dp[1] = val.y; dp[2] = val.z; dp[3] = val.w;
  }
  __syncthreads();
  int n = t & 31, cg = t >> 5;
  float a0 = 0.f, a1 = 0.f, a2 = 0.f, a3 = 0.f;
  for (int k = 0; k < 128; ++k) {
    float xv = Xs[n * 129 + k];
    const float* wr = &Ws[k * 32 + cg * 4];
    a0 += xv * wr[0]; a1 += xv * wr[1]; a2 += xv * wr[2]; a3 += xv * wr[3];
  }
  int node = nb + n;
  if (node < N) {
    int c = cg * 4;
    float* op = (c < 16) ? (y + (size_t)node * 16 + c)
                         : (z + (size_t)node * 16 + (c - 16));
    op[0] = a0; op[1] = a1; op[2] = a2; op[3] = a3;
  }
}

// CSR gather mean -> h=relu(+b1+z) -> p=h@W2l, q=h@W2r ; 16 lanes/node
__global__ __launch_bounds__(256) void agg1_kernel(const float* __restrict__ y,
                                                   const float* __restrict__ z,
                                                   const int* __restrict__ row_csr,
                                                   const int* __restrict__ srclist,
                                                   const float* __restrict__ b1,
                                                   const float* __restrict__ W2l,
                                                   const float* __restrict__ W2r,
                                                   float* __restrict__ p,
                                                   float* __restrict__ q, int N) {
  int g = (blockIdx.x * 256 + threadIdx.x) >> 4;
  int k = threadIdx.x & 15;
  if (g >= N) return;
  int beg = row_csr[g], end = row_csr[g + 1];
  float acc = 0.f;
  int j = beg;
  for (; j + 4 <= end; j += 4) {
    int s0 = srclist[j], s1 = srclist[j + 1];
    int s2 = srclist[j + 2], s3 = srclist[j + 3];
    acc += y[(size_t)s0 * 16 + k];
    acc += y[(size_t)s1 * 16 + k];
    acc += y[(size_t)s2 * 16 + k];
    acc += y[(size_t)s3 * 16 + k];
  }
  for (; j < end; ++j) acc += y[(size_t)srclist[j] * 16 + k];
  int deg = end - beg;
  float mean = acc / (float)(deg > 0 ? deg : 1);
  float h = fmaxf(mean + b1[k] + z[(size_t)g * 16 + k], 0.f);
  float pa = 0.f, qa = 0.f;
#pragma unroll
  for (int kk = 0; kk < 16; ++kk) {
    float hk = __shfl(h, kk, 16);
    pa += hk * W2l[kk * 16 + k];
    qa += hk * W2r[kk * 16 + k];
  }
  p[(size_t)g * 16 + k] = pa;
  q[(size_t)g * 16 + k] = qa;
}

// CSR gather mean -> h=relu(+b2+q) -> u=h@Wc[:16], v=h@Wc[16:]
__global__ __launch_bounds__(256) void agg2_kernel(const float* __restrict__ p,
                                                   const float* __restrict__ q,
                                                   const int* __restrict__ row_csr,
                                                   const int* __restrict__ srclist,
                                                   const float* __restrict__ b2,
                                                   const float* __restrict__ Wc,
                                                   float* __restrict__ U,
                                                   float* __restrict__ V, int N) {
  int g = (blockIdx.x * 256 + threadIdx.x) >> 4;
  int k = threadIdx.x & 15;
  if (g >= N) return;
  int beg = row_csr[g], end = row_csr[g + 1];
  float acc = 0.f;
  int j = beg;
  for (; j + 4 <= end; j += 4) {
    int s0 = srclist[j], s1 = srclist[j + 1];
    int s2 = srclist[j + 2], s3 = srclist[j + 3];
    acc += p[(size_t)s0 * 16 + k];
    acc += p[(size_t)s1 * 16 + k];
    acc += p[(size_t)s2 * 16 + k];
    acc += p[(size_t)s3 * 16 + k];
  }
  for (; j < end; ++j) acc += p[(size_t)srclist[j] * 16 + k];
  int deg = end - beg;
  float mean = acc / (float)(deg > 0 ? deg : 1);
  float h = fmaxf(mean + b2[k] + q[(size_t)g * 16 + k], 0.f);
  int wbase = (k < 8) ? 0 : 16;
  int c = k & 7;
  float o = 0.f;
#pragma unroll
  for (int kk = 0; kk < 16; ++kk) {
    float hk = __shfl(h, kk, 16);
    o += hk * Wc[(wbase + kk) * 8 + c];
  }
  if (k < 8) U[(size_t)g * 8 + c] = o;
  else       V[(size_t)g * 8 + c] = o;
}

__global__ __launch_bounds__(256) void edge_out_kernel(const int* __restrict__ ei,
                                                       const float* __restrict__ U,
                                                       const float* __restrict__ V,
                                                       const float* __restrict__ bc,
                                                       float* __restrict__ out, int E) {
  int e = blockIdx.x * 256 + threadIdx.x;
  if (e >= E) return;
  int src = ei[e];
  int dst = ei[E + e];
  const float4* up = (const float4*)(U + (size_t)src * 8);
  const float4* vp = (const float4*)(V + (size_t)dst * 8);
  float4 a0 = up[0], a1 = up[1];
  float4 b0 = vp[0], b1 = vp[1];
  float4 c0 = ((const float4*)bc)[0], c1 = ((const float4*)bc)[1];
  float t[8];
  t[0] = a0.x + b0.x + c0.x; t[1] = a0.y + b0.y + c0.y;
  t[2] = a0.z + b0.z + c0.z; t[3] = a0.w + b0.w + c0.w;
  t[4] = a1.x + b1.x + c1.x; t[5] = a1.y + b1.y + c1.y;
  t[6] = a1.z + b1.z + c1.z; t[7] = a1.w + b1.w + c1.w;
  float m = t[0];
#pragma unroll
  for (int c = 1; c < 8; ++c) m = fmaxf(m, t[c]);
  float s = 0.f;
#pragma unroll
  for (int c = 0; c < 8; ++c) s += __expf(t[c] - m);
  float lse = m + __logf(s);
  float4 o0 = make_float4(t[0] - lse, t[1] - lse, t[2] - lse, t[3] - lse);
  float4 o1 = make_float4(t[4] - lse, t[5] - lse, t[6] - lse, t[7] - lse);
  float4* op = (float4*)(out + (size_t)e * 8);
  op[0] = o0; op[1] = o1;
}

extern "C" void kernel_launch(void* const* d_in, const int* in_sizes, int n_in,
                              void* d_out, int out_size, void* d_ws, size_t ws_size,
                              hipStream_t stream) {
  const float* x   = (const float*)d_in[0];
  const int*   ei  = (const int*)d_in[1];
  const float* W1l = (const float*)d_in[2];
  const float* b1  = (const float*)d_in[3];
  const float* W1r = (const float*)d_in[4];
  const float* W2l = (const float*)d_in[5];
  const float* b2  = (const float*)d_in[6];
  const float* W2r = (const float*)d_in[7];
  const float* Wc  = (const float*)d_in[8];
  const float* bc  = (const float*)d_in[9];
  float* out = (float*)d_out;

  const int N = in_sizes[0] / 128;   // 100000
  const int E = in_sizes[1] / 2;     // 3200000
  const size_t N16 = (size_t)N * 16;
  const int NB = (N + BUCKET_SZ - 1) >> BUCKET_BITS;   // 196
  const int chunk = (E + NBLK - 1) / NBLK;

  float* A = (float*)d_ws;               // y, later u
  float* B = A + N16;                    // z, later v
  float* C = B + N16;                    // p
  float* D = C + N16;                    // q
  int* counts  = (int*)(D + N16);        // NB*NBLK
  int* locoff  = counts + NB * NBLK;     // NB*NBLK
  int* total   = locoff + NB * NBLK;     // NB
  int* bstart  = total + NB;             // NB + 1
  int* elist   = bstart + NB + 1;        // E  (packed, then in-place sorted src)
  int* row_csr = elist + E;              // N + 1

  bincount_kernel<<<NBLK, 512, 0, stream>>>(ei, counts, E, NB, chunk);
  scan1_kernel<<<NB, 512, 0, stream>>>(counts, locoff, total);
  scan2_kernel<<<1, 256, 0, stream>>>(total, bstart, NB);
  binwrite_kernel<<<NBLK, 512, 0, stream>>>(ei, locoff, bstart, elist, E, NB, chunk);
  size_t smem = (STAGE_CAP + 512 + 16) * sizeof(int);   // ~146 KB
  sort_kernel<<<NB, 1024, smem, stream>>>(elist, bstart, row_csr, N);

  lin1_kernel<<<(N + 31) / 32, 256, 0, stream>>>(x, W1l, W1r, A, B, N);

  int ngrid = (N * 16 + 255) / 256;
  agg1_kernel<<<ngrid, 256, 0, stream>>>(A, B, row_csr, elist, b1, W2l, W2r, C, D, N);
  agg2_kernel<<<ngrid, 256, 0, stream>>>(C, D, row_csr, elist, b2, Wc, A, B, N);

  int egrid = (E + 255) / 256;
  edge_out_kernel<<<egrid, 256, 0, stream>>>(ei, A, B, bc, out, E);
}